// Round 4
// baseline (341.163 us; speedup 1.0000x reference)
//
#include <hip/hip_runtime.h>

// Problem constants (fixed by setup_inputs)
constexpr int H_  = 32;
constexpr int N_  = 256;
constexpr int BS_ = 32;
constexpr int W_  = 128;
constexpr int T_  = 4096;
constexpr int D_  = 128;
constexpr int NQ_ = 8192;          // N_*BS_
constexpr float SCALE_  = 0.08838834764831845f;  // 1/sqrt(128)
constexpr float L2E_    = 1.4426950408889634f;
constexpr float MFLOOR_ = -1.0e28f;
constexpr float DEFER_  = 8.0f;                  // defer-max threshold (T13)

typedef __attribute__((ext_vector_type(4))) float f4;
typedef __attribute__((ext_vector_type(8))) short s8;
typedef __attribute__((ext_vector_type(4))) float fx4;

// one v_cvt_pk_bf16_f32: D.lo = bf16(a), D.hi = bf16(b)  (RNE)
__device__ __forceinline__ int pack2(float a, float b) {
  int r;
  asm("v_cvt_pk_bf16_f32 %0, %1, %2" : "=v"(r) : "v"(a), "v"(b));
  return r;
}

union frag_u { int w[4]; s8 v; };

__global__ __launch_bounds__(128, 3)
void mtp_attn_kernel(const float* __restrict__ q,
                     const float* __restrict__ k_ctx,
                     const float* __restrict__ v_ctx,
                     const float* __restrict__ k_draft,
                     const float* __restrict__ v_draft,
                     const int* __restrict__ anchor,
                     const int* __restrict__ keepm,
                     float* __restrict__ out)
{
  // XCD-chunked swizzle (8192 % 8 == 0 -> bijective)
  int u = blockIdx.x;
  u = (u & 7) * 1024 + (u >> 3);
  const int h = u >> 8;
  const int n = u & 255;

  const int tu   = threadIdx.x;  // 0..127; two fully independent waves (no LDS, no barriers)
  const int lane = tu & 63;
  const int wu   = tu >> 6;      // wave id: queries wu*16..+15
  const int l15  = lane & 15;
  const int g    = lane >> 4;    // 0..3

  const int A  = anchor[n];
  const int kp = keepm[n];
  const int wm = W_ - A;         // ctx key valid iff key >= wm

  // ---- Q B-fragments (bf16 via cvt_pk), kept in registers ----
  const float* qrow = q + ((size_t)h * NQ_ + (size_t)n * BS_ + wu * 16 + l15) * D_;
  s8 qb[4];
#pragma unroll
  for (int ks = 0; ks < 4; ++ks) {
    f4 f0 = *reinterpret_cast<const f4*>(qrow + ks * 32 + g * 4);
    f4 f1 = *reinterpret_cast<const f4*>(qrow + ks * 32 + 16 + g * 4);
    frag_u uq;
    uq.w[0] = pack2(f0[0], f0[1]); uq.w[1] = pack2(f0[2], f0[3]);
    uq.w[2] = pack2(f1[0], f1[1]); uq.w[3] = pack2(f1[2], f1[3]);
    qb[ks] = uq.v;
  }

  // global source bases
  const float* kcb = k_ctx + (size_t)h * T_ * D_;
  const float* vcb = v_ctx + (size_t)h * T_ * D_;
  const float* kdb = k_draft + ((size_t)h * NQ_ + (size_t)n * BS_) * D_;
  const float* vdb = v_draft + ((size_t)h * NQ_ + (size_t)n * BS_) * D_;

  float m  = -3.0e38f;
  float ls = 0.0f;
  fx4 oacc[8];
#pragma unroll
  for (int t = 0; t < 8; ++t) oacc[t] = {0.f, 0.f, 0.f, 0.f};

#pragma unroll
  for (int c = 0; c < 5; ++c) {
    // ---- per-chunk row bases ----
    // K rows for the two 16-key tiles (this lane reads row t2*16+l15)
    const float* kr0; const float* kr1;
    if (c < 4) {
      int i0 = A - W_ + c * 32 + l15;      int i1 = i0 + 16;
      i0 = i0 < 0 ? 0 : i0;                i1 = i1 < 0 ? 0 : i1;
      kr0 = kcb + (size_t)i0 * D_;         kr1 = kcb + (size_t)i1 * D_;
    } else {
      kr0 = kdb + (size_t)l15 * D_;        kr1 = kr0 + 16 * D_;
    }
    // V element offsets: frag element j reads V[key = g*4+(j&3)+16*(j>>2)][d = nt*16+l15]
    const float* vbase = (c < 4) ? vcb : vdb;
    int voff[8];
#pragma unroll
    for (int j = 0; j < 8; ++j) {
      int k = g * 4 + (j & 3) + 16 * (j >> 2);
      if (c < 4) { int idx = A - W_ + c * 32 + k; idx = idx < 0 ? 0 : idx; voff[j] = idx * D_ + l15; }
      else       { voff[j] = k * D_ + l15; }
    }

    // ---- V fragment loads (issued early; land during QK compute), packed to bf16 ----
    int vw[32];
#pragma unroll
    for (int nt = 0; nt < 8; ++nt)
#pragma unroll
      for (int jp = 0; jp < 4; ++jp)
        vw[nt * 4 + jp] = pack2(vbase[voff[jp * 2] + nt * 16],
                                vbase[voff[jp * 2 + 1] + nt * 16]);

    // ---- QK^T swapped: st = mfma(K, Q) -> lane holds S^T[key][q=l15] ----
    fx4 st[2] = { {0.f,0.f,0.f,0.f}, {0.f,0.f,0.f,0.f} };
    __builtin_amdgcn_s_setprio(1);
#pragma unroll
    for (int ks = 0; ks < 4; ++ks) {
#pragma unroll
      for (int t2 = 0; t2 < 2; ++t2) {
        const float* kr = t2 ? kr1 : kr0;
        f4 f0 = *reinterpret_cast<const f4*>(kr + ks * 32 + g * 4);
        f4 f1 = *reinterpret_cast<const f4*>(kr + ks * 32 + 16 + g * 4);
        frag_u uk;
        uk.w[0] = pack2(f0[0], f0[1]); uk.w[1] = pack2(f0[2], f0[3]);
        uk.w[2] = pack2(f1[0], f1[1]); uk.w[3] = pack2(f1[2], f1[3]);
        st[t2] = __builtin_amdgcn_mfma_f32_16x16x32_bf16(uk.v, qb[ks], st[t2], 0, 0, 0);
      }
    }
    __builtin_amdgcn_s_setprio(0);

    // ---- mask + scale + chunk max (per query q = l15) ----
    float sv[2][4];
    float cm = -3.0e38f;
#pragma unroll
    for (int t2 = 0; t2 < 2; ++t2) {
      int kb0 = c * 32 + t2 * 16 + g * 4;
#pragma unroll
      for (int r = 0; r < 4; ++r) {
        float v = st[t2][r] * SCALE_;
        bool valid = (c == 4) || (kb0 + r >= wm);
        v = valid ? v : -1.0e30f;
        sv[t2][r] = v;
        cm = fmaxf(cm, v);
      }
    }
    cm = fmaxf(cm, __shfl_xor(cm, 16));
    cm = fmaxf(cm, __shfl_xor(cm, 32));

    // ---- online max with defer threshold ----
    if (c == 0) {
      m = fmaxf(cm, MFLOOR_);
    } else {
      float pm = fmaxf(m, cm);
      if (!__all(pm - m <= DEFER_)) {
        float mn = fmaxf(pm, MFLOOR_);
        float al = exp2f((m - mn) * L2E_);
        ls *= al;
        float alr[4];
#pragma unroll
        for (int r = 0; r < 4; ++r) alr[r] = __shfl(al, g * 4 + r);
#pragma unroll
        for (int nt = 0; nt < 8; ++nt)
#pragma unroll
          for (int r = 0; r < 4; ++r) oacc[nt][r] *= alr[r];
        m = mn;
      }
    }

    // ---- p = exp, accumulate l, pack PV A-fragment (lane-local, no shuffles) ----
    s8 pa;
#pragma unroll
    for (int t2 = 0; t2 < 2; ++t2)
#pragma unroll
      for (int r = 0; r < 4; ++r) {
        float p = exp2f((sv[t2][r] - m) * L2E_);
        ls += p;
        reinterpret_cast<unsigned short*>(&pa)[t2 * 4 + r] =
            (unsigned short)(pack2(p, p) & 0xffff);
      }

    // ---- PV: O[q][d] += P * V ----
    __builtin_amdgcn_s_setprio(1);
#pragma unroll
    for (int nt = 0; nt < 8; ++nt) {
      frag_u uv;
      uv.w[0] = vw[nt * 4 + 0]; uv.w[1] = vw[nt * 4 + 1];
      uv.w[2] = vw[nt * 4 + 2]; uv.w[3] = vw[nt * 4 + 3];
      oacc[nt] = __builtin_amdgcn_mfma_f32_16x16x32_bf16(pa, uv.v, oacc[nt], 0, 0, 0);
    }
    __builtin_amdgcn_s_setprio(0);
  }

  // ---- epilogue: reduce l across key-groups, redistribute, normalize, store ----
  ls += __shfl_xor(ls, 16);
  ls += __shfl_xor(ls, 32);
  float linv[4];
#pragma unroll
  for (int r = 0; r < 4; ++r) {
    float lq = __shfl(ls, g * 4 + r);
    linv[r] = kp ? (1.0f / lq) : 0.0f;
  }
  float* ob = out + ((size_t)h * NQ_ + (size_t)n * BS_ + wu * 16 + g * 4) * D_ + l15;
#pragma unroll
  for (int nt = 0; nt < 8; ++nt)
#pragma unroll
    for (int r = 0; r < 4; ++r)
      ob[(size_t)r * D_ + nt * 16] = oacc[nt][r] * linv[r];
}

extern "C" void kernel_launch(void* const* d_in, const int* in_sizes, int n_in,
                              void* d_out, int out_size, void* d_ws, size_t ws_size,
                              hipStream_t stream) {
  (void)in_sizes; (void)n_in; (void)d_ws; (void)ws_size; (void)out_size;
  const float* q       = (const float*)d_in[0];
  const float* k_ctx   = (const float*)d_in[1];
  const float* v_ctx   = (const float*)d_in[2];
  const float* k_draft = (const float*)d_in[3];
  const float* v_draft = (const float*)d_in[4];
  const int*   anchor  = (const int*)d_in[5];
  const int*   keep    = (const int*)d_in[6];
  float*       out     = (float*)d_out;
  mtp_attn_kernel<<<dim3(8192), dim3(128), 0, stream>>>(
      q, k_ctx, v_ctx, k_draft, v_draft, anchor, keep, out);
}

// Round 5
// 158.219 us; speedup vs baseline: 2.1563x; 2.1563x over previous
//
#include <hip/hip_runtime.h>

// Problem constants (fixed by setup_inputs)
constexpr int H_  = 32;
constexpr int N_  = 256;
constexpr int BS_ = 32;
constexpr int W_  = 128;
constexpr int T_  = 4096;
constexpr int D_  = 128;
constexpr int NQ_ = 8192;          // N_*BS_
constexpr float SCALE_  = 0.08838834764831845f;  // 1/sqrt(128)
constexpr float L2E_    = 1.4426950408889634f;
constexpr float MFLOOR_ = -1.0e28f;
constexpr float DEFER_  = 8.0f;                  // defer-max threshold (T13)

typedef __attribute__((ext_vector_type(4))) float f4;
typedef __attribute__((ext_vector_type(4))) short s4;
typedef __attribute__((ext_vector_type(8))) short s8;
typedef __attribute__((ext_vector_type(4))) float fx4;
typedef __attribute__((ext_vector_type(2))) int i2;

// one v_cvt_pk_bf16_f32: D.lo = bf16(a), D.hi = bf16(b)  (RNE)
__device__ __forceinline__ int pack2(float a, float b) {
  int r;
  asm("v_cvt_pk_bf16_f32 %0, %1, %2" : "=v"(r) : "v"(a), "v"(b));
  return r;
}

union frag_u { int w[4]; s8 v; };

// Workgroup barrier draining ONLY lgkmcnt; reg-dest global loads stay in flight.
__device__ __forceinline__ void lds_barrier() {
  asm volatile("s_waitcnt lgkmcnt(0)" ::: "memory");
  __builtin_amdgcn_s_barrier();
}

__global__ __launch_bounds__(128, 2)
void mtp_attn_kernel(const float* __restrict__ q,
                     const float* __restrict__ k_ctx,
                     const float* __restrict__ v_ctx,
                     const float* __restrict__ k_draft,
                     const float* __restrict__ v_draft,
                     const int* __restrict__ anchor,
                     const int* __restrict__ keepm,
                     float* __restrict__ out)
{
  // XCD-chunked swizzle (8192 % 8 == 0 -> bijective)
  int u = blockIdx.x;
  u = (u & 7) * 1024 + (u >> 3);
  const int h = u >> 8;
  const int n = u & 255;

  const int tu   = threadIdx.x;  // 0..127
  const int lane = tu & 63;
  const int wu   = tu >> 6;      // wave id: queries wu*16..+15
  const int l15  = lane & 15;
  const int g    = lane >> 4;    // 0..3
  const int rb   = tu >> 5;      // 0..3 (staging row group)
  const int c4   = tu & 31;      // staging float4 column

  const int A  = anchor[n];
  const int kp = keepm[n];
  const int wm = W_ - A;         // ctx key valid iff key >= wm

  // LDS: K chunk bf16 [32][132] (8448B) + V^T chunk bf16 [128][36] (9216B) = 17664B
  __shared__ __align__(16) unsigned char smem_[17664];
  short* kb = (short*)smem_;
  short* vT = (short*)(smem_ + 8448);

  // ---- Q B-fragments (bf16 via cvt_pk), kept in registers ----
  const float* qrow = q + ((size_t)h * NQ_ + (size_t)n * BS_ + wu * 16 + l15) * D_;
  s8 qb[4];
#pragma unroll
  for (int ks = 0; ks < 4; ++ks) {
    f4 f0 = *reinterpret_cast<const f4*>(qrow + ks * 32 + g * 4);
    f4 f1 = *reinterpret_cast<const f4*>(qrow + ks * 32 + 16 + g * 4);
    frag_u uq;
    uq.w[0] = pack2(f0[0], f0[1]); uq.w[1] = pack2(f0[2], f0[3]);
    uq.w[2] = pack2(f1[0], f1[1]); uq.w[3] = pack2(f1[2], f1[3]);
    qb[ks] = uq.v;
  }

  // global source bases
  const float* kcb = k_ctx + (size_t)h * T_ * D_;
  const float* vcb = v_ctx + (size_t)h * T_ * D_;
  const float* kdb = k_draft + ((size_t)h * NQ_ + (size_t)n * BS_) * D_;
  const float* vdb = v_draft + ((size_t)h * NQ_ + (size_t)n * BS_) * D_;

  auto loadK = [&](f4 (&dst)[8], int c) {
#pragma unroll
    for (int i = 0; i < 8; ++i) {
      int row = i * 4 + rb;
      const float* src;
      if (c < 4) { int idx = A - W_ + c * 32 + row; idx = idx < 0 ? 0 : idx; src = kcb + (size_t)idx * D_; }
      else       { src = kdb + (size_t)row * D_; }
      dst[i] = reinterpret_cast<const f4*>(src)[c4];
    }
  };
  auto loadV = [&](f4 (&dst)[8], int c) {
#pragma unroll
    for (int p = 0; p < 2; ++p)
#pragma unroll
      for (int i = 0; i < 4; ++i) {
        int row = p * 16 + rb * 4 + i;
        const float* src;
        if (c < 4) { int idx = A - W_ + c * 32 + row; idx = idx < 0 ? 0 : idx; src = vcb + (size_t)idx * D_; }
        else       { src = vdb + (size_t)row * D_; }
        dst[p * 4 + i] = reinterpret_cast<const f4*>(src)[c4];
      }
  };

  // ---- depth-2 prefetch: chunk c lives in set (c & 1) ----
  f4 krA[8], vrA[8], krB[8], vrB[8];
  loadK(krA, 0); loadV(vrA, 0);
  loadK(krB, 1); loadV(vrB, 1);

  float m  = -3.0e38f;
  float ls = 0.0f;
  fx4 oacc[8];
#pragma unroll
  for (int t = 0; t < 8; ++t) oacc[t] = {0.f, 0.f, 0.f, 0.f};

#pragma unroll
  for (int c = 0; c < 5; ++c) {
    f4 (&kr)[8] = (c & 1) ? krB : krA;   // compile-time under full unroll
    f4 (&vr)[8] = (c & 1) ? vrB : vrA;

    lds_barrier();                 // LDS chunk c-1 fully consumed
    // ---- write staged chunk c to LDS (bf16 via cvt_pk) ----
#pragma unroll
    for (int i = 0; i < 8; ++i) {
      i2 w = { pack2(kr[i][0], kr[i][1]), pack2(kr[i][2], kr[i][3]) };
      *reinterpret_cast<i2*>(kb + (i * 4 + rb) * 132 + c4 * 4) = w;
    }
#pragma unroll
    for (int p = 0; p < 2; ++p) {
      int keyl = p * 16 + rb * 4;
#pragma unroll
      for (int j = 0; j < 4; ++j) {   // 4x4 transpose -> vT[d][key]
        i2 w = { pack2(vr[p * 4 + 0][j], vr[p * 4 + 1][j]),
                 pack2(vr[p * 4 + 2][j], vr[p * 4 + 3][j]) };
        *reinterpret_cast<i2*>(vT + (c4 * 4 + j) * 36 + keyl) = w;
      }
    }
    // ---- reissue this set for chunk c+2 (has ~2 full iterations to land) ----
    if (c < 3) { loadK(kr, c + 2); loadV(vr, c + 2); }
    lds_barrier();                 // LDS chunk c ready

    // ---- QK^T swapped: st = mfma(K, Q) -> lane holds S^T[key][q=l15] ----
    fx4 st[2] = { {0.f,0.f,0.f,0.f}, {0.f,0.f,0.f,0.f} };
    __builtin_amdgcn_s_setprio(1);
#pragma unroll
    for (int ks = 0; ks < 4; ++ks) {
#pragma unroll
      for (int t2 = 0; t2 < 2; ++t2) {
        const short* kpr = kb + (t2 * 16 + l15) * 132 + ks * 32 + g * 4;
        s4 b0 = *reinterpret_cast<const s4*>(kpr);
        s4 b1 = *reinterpret_cast<const s4*>(kpr + 16);
        s8 kf = { b0[0], b0[1], b0[2], b0[3], b1[0], b1[1], b1[2], b1[3] };
        st[t2] = __builtin_amdgcn_mfma_f32_16x16x32_bf16(kf, qb[ks], st[t2], 0, 0, 0);
      }
    }
    __builtin_amdgcn_s_setprio(0);

    // ---- mask + scale + chunk max (per query q = l15) ----
    float sv[2][4];
    float cm = -3.0e38f;
#pragma unroll
    for (int t2 = 0; t2 < 2; ++t2) {
      int kb0 = c * 32 + t2 * 16 + g * 4;
#pragma unroll
      for (int r = 0; r < 4; ++r) {
        float v = st[t2][r] * SCALE_;
        bool valid = (c == 4) || (kb0 + r >= wm);
        v = valid ? v : -1.0e30f;
        sv[t2][r] = v;
        cm = fmaxf(cm, v);
      }
    }
    cm = fmaxf(cm, __shfl_xor(cm, 16));
    cm = fmaxf(cm, __shfl_xor(cm, 32));

    // ---- online max with defer threshold ----
    if (c == 0) {
      m = fmaxf(cm, MFLOOR_);
    } else {
      float pm = fmaxf(m, cm);
      if (!__all(pm - m <= DEFER_)) {
        float mn = fmaxf(pm, MFLOOR_);
        float al = exp2f((m - mn) * L2E_);
        ls *= al;
        float alr[4];
#pragma unroll
        for (int r = 0; r < 4; ++r) alr[r] = __shfl(al, g * 4 + r);
#pragma unroll
        for (int nt = 0; nt < 8; ++nt)
#pragma unroll
          for (int r = 0; r < 4; ++r) oacc[nt][r] *= alr[r];
        m = mn;
      }
    }

    // ---- p = exp, accumulate l, pack PV A-fragment (lane-local) ----
    float pv[8];
#pragma unroll
    for (int t2 = 0; t2 < 2; ++t2)
#pragma unroll
      for (int r = 0; r < 4; ++r) {
        float p = exp2f((sv[t2][r] - m) * L2E_);
        ls += p;
        pv[t2 * 4 + r] = p;
      }
    frag_u up;
    up.w[0] = pack2(pv[0], pv[1]); up.w[1] = pack2(pv[2], pv[3]);
    up.w[2] = pack2(pv[4], pv[5]); up.w[3] = pack2(pv[6], pv[7]);
    s8 pa = up.v;

    // ---- PV: O[q][d] += P * V ----
    __builtin_amdgcn_s_setprio(1);
#pragma unroll
    for (int nt = 0; nt < 8; ++nt) {
      const short* vp = vT + (nt * 16 + l15) * 36 + g * 4;
      s4 b0 = *reinterpret_cast<const s4*>(vp);
      s4 b1 = *reinterpret_cast<const s4*>(vp + 16);
      s8 vb2 = { b0[0], b0[1], b0[2], b0[3], b1[0], b1[1], b1[2], b1[3] };
      oacc[nt] = __builtin_amdgcn_mfma_f32_16x16x32_bf16(pa, vb2, oacc[nt], 0, 0, 0);
    }
    __builtin_amdgcn_s_setprio(0);
  }

  // ---- epilogue: reduce l across key-groups, redistribute, normalize, store ----
  ls += __shfl_xor(ls, 16);
  ls += __shfl_xor(ls, 32);
  float linv[4];
#pragma unroll
  for (int r = 0; r < 4; ++r) {
    float lq = __shfl(ls, g * 4 + r);
    linv[r] = kp ? (1.0f / lq) : 0.0f;
  }
  float* ob = out + ((size_t)h * NQ_ + (size_t)n * BS_ + wu * 16 + g * 4) * D_ + l15;
#pragma unroll
  for (int nt = 0; nt < 8; ++nt)
#pragma unroll
    for (int r = 0; r < 4; ++r)
      ob[(size_t)r * D_ + nt * 16] = oacc[nt][r] * linv[r];
}

extern "C" void kernel_launch(void* const* d_in, const int* in_sizes, int n_in,
                              void* d_out, int out_size, void* d_ws, size_t ws_size,
                              hipStream_t stream) {
  (void)in_sizes; (void)n_in; (void)d_ws; (void)ws_size; (void)out_size;
  const float* q       = (const float*)d_in[0];
  const float* k_ctx   = (const float*)d_in[1];
  const float* v_ctx   = (const float*)d_in[2];
  const float* k_draft = (const float*)d_in[3];
  const float* v_draft = (const float*)d_in[4];
  const int*   anchor  = (const int*)d_in[5];
  const int*   keep    = (const int*)d_in[6];
  float*       out     = (float*)d_out;
  mtp_attn_kernel<<<dim3(8192), dim3(128), 0, stream>>>(
      q, k_ctx, v_ctx, k_draft, v_draft, anchor, keep, out);
}